// Round 2
// baseline (257.874 us; speedup 1.0000x reference)
//
#include <hip/hip_runtime.h>

// Bilinear sampling: x is (B=128, H=224, W=224, 5) f32 interleaved
// [r,g,b,X,Y]; out is (B,224,224,3) f32.
//
// R4b: same as R4, with NT stores via native clang vector type
// (__builtin_nontemporal_store rejects HIP_vector_type float4).
//  - 4 CONSECUTIVE pixels per thread: the 80B input span is 5 aligned
//    coalesced dwordx4 loads, and all 16 gathers issue back-to-back
//    -> ~3-4x outstanding VMEM per wave (latency/MLP-bound theory).
//  - Non-temporal stores (3 aligned 16B/thread) so the 77MB write-once
//    output stream doesn't evict the per-image L2 gather working set.
//  - XCD swizzle (image b pinned to XCD b&7) + paired-float4 corner trick.
// Inputs guarantee X,Y in [0,223) so the reference's pad/clip never fires.

#define HH 224
#define WW 224
#define NB 128

constexpr int PIX_PER_IMG    = HH * WW;                      // 50176
constexpr int BLOCK          = 256;
constexpr int P              = 4;                            // consecutive pixels/thread
constexpr int PIX_PER_BLOCK  = BLOCK * P;                    // 1024
constexpr int BLOCKS_PER_IMG = PIX_PER_IMG / PIX_PER_BLOCK;  // 49 (exact)
constexpr int TOTAL_BLOCKS   = NB * BLOCKS_PER_IMG;          // 6272
constexpr int ROW_BYTES      = WW * 5 * 4;                   // 4480

typedef float f32x4 __attribute__((ext_vector_type(4)));

__device__ __forceinline__ float4 ld4(const float* p) {
    return *reinterpret_cast<const float4*>(p);
}

__global__ __launch_bounds__(BLOCK) void bilinear_kernel(
    const float* __restrict__ x, float* __restrict__ out)
{
    // XCD-aware swizzle: all blocks of image b land on XCD (b & 7).
    int i    = blockIdx.x;
    int xcd  = i & 7;
    int slot = i >> 3;
    int b    = xcd + 8 * (slot / BLOCKS_PER_IMG);
    int tile = slot % BLOCKS_PER_IMG;
    int pix0 = tile * PIX_PER_BLOCK + (int)threadIdx.x * P;

    const float* img = x + (size_t)b * (PIX_PER_IMG * 5);
    const float* xp  = img + (size_t)pix0 * 5;

    // This thread's 4 pixels = 20 contiguous floats [r,g,b,X,Y]x4,
    // 80B-aligned -> 5 coalesced dwordx4 loads.
    float4 v0 = ld4(xp +  0);
    float4 v1 = ld4(xp +  4);
    float4 v2 = ld4(xp +  8);
    float4 v3 = ld4(xp + 12);
    float4 v4 = ld4(xp + 16);

    // pixel k: X at float 5k+3, Y at float 5k+4
    float Xs[P] = { v0.w, v2.x, v3.y, v4.z };
    float Ys[P] = { v1.x, v2.y, v3.z, v4.w };

    float4 a0[P], b0[P], a1[P], b1[P];
    float  wx[P], wy[P];
    const char* base = reinterpret_cast<const char*>(img);

    // Issue all 16 gathers before any combine -> max memory-level parallelism.
#pragma unroll
    for (int k = 0; k < P; ++k) {
        float fx = floorf(Xs[k]);
        float fy = floorf(Ys[k]);
        wx[k] = Xs[k] - fx;
        wy[k] = Ys[k] - fy;
        // byte offset = (fyi*224 + fxi)*20; exact in fp32 (all ints < 2^24)
        int voff = (int)fmaf(fy, (float)ROW_BYTES, fx * 20.0f);
        const char* q0 = base + voff;                    // row fyi, col fxi
        a0[k] = ld4(reinterpret_cast<const float*>(q0));          // r,g,b,(X)
        b0[k] = ld4(reinterpret_cast<const float*>(q0 + 16));     // (Y),r',g',b'
        a1[k] = ld4(reinterpret_cast<const float*>(q0 + ROW_BYTES));
        b1[k] = ld4(reinterpret_cast<const float*>(q0 + ROW_BYTES + 16));
    }

    float o[3 * P];
#pragma unroll
    for (int k = 0; k < P; ++k) {
        float w_tl = (1.f - wx[k]) * (1.f - wy[k]);
        float w_tr = wx[k] * (1.f - wy[k]);
        float w_bl = (1.f - wx[k]) * wy[k];
        float w_br = wx[k] * wy[k];
        o[3*k+0] = w_tl*a0[k].x + w_tr*b0[k].y + w_bl*a1[k].x + w_br*b1[k].y;
        o[3*k+1] = w_tl*a0[k].y + w_tr*b0[k].z + w_bl*a1[k].y + w_br*b1[k].z;
        o[3*k+2] = w_tl*a0[k].z + w_tr*b0[k].w + w_bl*a1[k].z + w_br*b1[k].w;
    }

    // 4 pixels * 12B = 48B contiguous, 48B-aligned -> 3 NT dwordx4 stores.
    float* op = out + ((size_t)b * PIX_PER_IMG + pix0) * 3;
    f32x4* ov = reinterpret_cast<f32x4*>(op);
    f32x4 s0 = { o[0], o[1], o[2],  o[3]  };
    f32x4 s1 = { o[4], o[5], o[6],  o[7]  };
    f32x4 s2 = { o[8], o[9], o[10], o[11] };
    __builtin_nontemporal_store(s0, ov + 0);
    __builtin_nontemporal_store(s1, ov + 1);
    __builtin_nontemporal_store(s2, ov + 2);
}

extern "C" void kernel_launch(void* const* d_in, const int* in_sizes, int n_in,
                              void* d_out, int out_size, void* d_ws, size_t ws_size,
                              hipStream_t stream) {
    const float* x = (const float*)d_in[0];
    float* out = (float*)d_out;
    bilinear_kernel<<<TOTAL_BLOCKS, BLOCK, 0, stream>>>(x, out);
}